// Round 1
// baseline (494.712 us; speedup 1.0000x reference)
//
#include <hip/hip_runtime.h>
#include <math.h>

// DFT_10316511445664: batched length-100 DFT, bins 50..99 (fftshift+crop),
// scaled by 1/100, split re/im -> [B,2,50], plus MVN logprob over the 100
// resulting components. Direct DFT: thread = sample, row in registers,
// twiddles via wave-uniform scalar loads from __device__ tables.

#define NFFT 100
#define CROP 50
#define BLOCK 256

// -0.5 * D * log(2*pi), D = 100
#define LOGPZ_CONST -91.893853320467274f

__device__ float g_wcos[CROP * NFFT];
__device__ float g_wsin[CROP * NFFT];

__global__ void init_twiddles_kernel() {
    int idx = blockIdx.x * blockDim.x + threadIdx.x;
    if (idx < CROP * NFFT) {
        int k = idx / NFFT;       // output bin 0..49  (freq m = 50+k)
        int n = idx - k * NFFT;   // tap 0..99
        int j = ((50 + k) * n) % 100;          // exact angle reduction
        float ang = (float)j * 0.06283185307179586477f;  // 2*pi/100
        g_wcos[idx] = cosf(ang);
        g_wsin[idx] = sinf(ang);
    }
}

__global__ __launch_bounds__(BLOCK) void dft_kernel(const float* __restrict__ x,
                                                    float* __restrict__ out,
                                                    int B) {
    // 64 rows staged per round; pad 101: lane stride 101 % 32 = 5, gcd(5,32)=1
    // -> 2-way (free) LDS bank aliasing on the transpose read.
    __shared__ float tile[64][101];

    const int tid  = threadIdx.x;
    const int wave = tid >> 6;
    const int lane = tid & 63;
    const int blockBase = blockIdx.x * BLOCK;   // first sample of this block

    float row[NFFT];

    // 4 rounds: stage 64 rows coalesced, wave r copies its rows to registers.
    for (int r = 0; r < 4; ++r) {
        const float* src = x + (blockBase + r * 64) * NFFT;
#pragma unroll
        for (int i = 0; i < 25; ++i) {
            int e  = tid + i * BLOCK;   // 0..6399 over 64 rows x 100 cols
            int rr = e / 100;
            int cc = e - rr * 100;
            tile[rr][cc] = src[e];
        }
        __syncthreads();
        if (wave == r) {
#pragma unroll
            for (int n = 0; n < NFFT; ++n) row[n] = tile[lane][n];
        }
        __syncthreads();
    }

    const int s = blockBase + tid;      // this thread's sample
    float* outr = out + s * (2 * CROP); // x_fft rows: [2,50] = 100 floats

    float s2 = 0.0f;
    for (int k = 0; k < CROP; ++k) {
        const float* wc = g_wcos + k * NFFT;  // uniform address -> s_load
        const float* ws = g_wsin + k * NFFT;
        float ar = 0.0f, ai = 0.0f;
#pragma unroll
        for (int n = 0; n < NFFT; ++n) {
            ar = fmaf(row[n], wc[n], ar);
            ai = fmaf(row[n], ws[n], ai);
        }
        // X[m] = sum x[n] (cos - i sin); scale by 1/N
        float re = ar * 0.01f;
        float im = ai * -0.01f;
        outr[k]        = re;
        outr[CROP + k] = im;
        s2 = fmaf(re, re, s2);
        s2 = fmaf(im, im, s2);
    }
    // log_pz, appended after the B*100 x_fft floats
    out[B * (2 * CROP) + s] = fmaf(s2, -0.5f, LOGPZ_CONST);
}

extern "C" void kernel_launch(void* const* d_in, const int* in_sizes, int n_in,
                              void* d_out, int out_size, void* d_ws, size_t ws_size,
                              hipStream_t stream) {
    const float* x = (const float*)d_in[0];
    float* out = (float*)d_out;
    const int B = in_sizes[0] / NFFT;   // 262144

    // Twiddle tables must be rebuilt every call (no persistent-state reliance).
    hipLaunchKernelGGL(init_twiddles_kernel, dim3((CROP * NFFT + BLOCK - 1) / BLOCK),
                       dim3(BLOCK), 0, stream);

    hipLaunchKernelGGL(dft_kernel, dim3(B / BLOCK), dim3(BLOCK), 0, stream, x, out, B);
}

// Round 2
// 237.669 us; speedup vs baseline: 2.0815x; 2.0815x over previous
//
#include <hip/hip_runtime.h>
#include <math.h>

// DFT_10316511445664 as a tiny GEMM: OUT[B,100] = X[B,100] . W^T, where
// W[j][n] = cos(2*pi*(50+j)*n/100)/100        (j < 50, real part, bins 50..99)
//         = -sin(2*pi*j*n/100)/100            (j >= 50, imag part, bin j)
// plus log_pz[s] = -0.5 * sum_j OUT[s][j]^2 - 0.5*100*log(2pi).
//
// Block = 64 samples; wave w owns 25 output columns; lane = sample.
// X staged in LDS [64][108] (16B-aligned rows, minimal b128 bank phases),
// W read via wave-uniform scalar loads (SGPR operand in v_fmac).
// Outputs staged back through LDS for fully coalesced stores.

#define NFFT 100
#define CROP 50
#define BLOCK 256
#define TM 64
#define STRIDE 108                       // floats per LDS row
#define LOGPZ_CONST -91.893853320467274f // -0.5*100*log(2*pi)

__device__ float g_W[NFFT * NFFT];

__global__ void init_w_kernel() {
    int idx = blockIdx.x * blockDim.x + threadIdx.x;
    if (idx < NFFT * NFFT) {
        int j = idx / NFFT;
        int n = idx - j * NFFT;
        int bin = (j < CROP) ? (CROP + j) : j;   // output frequency index
        int t = (bin * n) % NFFT;                // exact angle reduction
        float ang = (float)t * 0.06283185307179586477f; // 2*pi/100
        g_W[idx] = ((j < CROP) ? cosf(ang) : -sinf(ang)) * 0.01f;
    }
}

__global__ __launch_bounds__(BLOCK) void dft_kernel(const float* __restrict__ x,
                                                    float* __restrict__ out,
                                                    int B) {
    __shared__ float tile[TM][STRIDE];
    __shared__ float p2[4][TM];

    const int tid  = threadIdx.x;
    const int lane = tid & 63;
    const int wv   = __builtin_amdgcn_readfirstlane(tid >> 6); // wave 0..3, uniform
    const int blockBase = blockIdx.x * TM;

    // ---- stage X tile, coalesced ----
    const float* __restrict__ src = x + (size_t)blockBase * NFFT;
#pragma unroll
    for (int i = 0; i < 25; ++i) {
        int e  = tid + i * BLOCK;        // 0..6399
        int rr = e / NFFT;
        int cc = e - rr * NFFT;
        tile[rr][cc] = src[e];
    }
    __syncthreads();

    // ---- GEMM inner loop: 25 accumulators, K=100 in float4 chunks ----
    const float* __restrict__ Wb = g_W + wv * 25 * NFFT;
    float acc[25];
#pragma unroll
    for (int j = 0; j < 25; ++j) acc[j] = 0.0f;

    const float4* __restrict__ xrow =
        reinterpret_cast<const float4*>(&tile[lane][0]); // 27 float4 per row

    for (int kc = 0; kc < 25; ++kc) {
        float4 xv = xrow[kc];            // ds_read_b128
#pragma unroll
        for (int j = 0; j < 25; ++j) {
            const float* wr = Wb + j * NFFT + kc * 4;  // wave-uniform -> s_load
            acc[j] = fmaf(xv.x, wr[0], acc[j]);
            acc[j] = fmaf(xv.y, wr[1], acc[j]);
            acc[j] = fmaf(xv.z, wr[2], acc[j]);
            acc[j] = fmaf(xv.w, wr[3], acc[j]);
        }
    }

    // ---- partial sum of squares for log_pz ----
    float s2 = 0.0f;
#pragma unroll
    for (int j = 0; j < 25; ++j) s2 = fmaf(acc[j], acc[j], s2);
    p2[wv][lane] = s2;

    __syncthreads();   // all waves done reading X tile

    // ---- stage OUT tile in LDS, then coalesced store ----
#pragma unroll
    for (int j = 0; j < 25; ++j) tile[lane][wv * 25 + j] = acc[j];
    __syncthreads();

    float* __restrict__ dst = out + (size_t)blockBase * NFFT;
#pragma unroll
    for (int i = 0; i < 25; ++i) {
        int e  = tid + i * BLOCK;
        int rr = e / NFFT;
        int cc = e - rr * NFFT;
        dst[e] = tile[rr][cc];
    }

    if (wv == 0) {
        float t = p2[0][lane] + p2[1][lane] + p2[2][lane] + p2[3][lane];
        out[(size_t)B * NFFT + blockBase + lane] = fmaf(t, -0.5f, LOGPZ_CONST);
    }
}

extern "C" void kernel_launch(void* const* d_in, const int* in_sizes, int n_in,
                              void* d_out, int out_size, void* d_ws, size_t ws_size,
                              hipStream_t stream) {
    const float* x = (const float*)d_in[0];
    float* out = (float*)d_out;
    const int B = in_sizes[0] / NFFT;   // 262144

    hipLaunchKernelGGL(init_w_kernel, dim3((NFFT * NFFT + BLOCK - 1) / BLOCK),
                       dim3(BLOCK), 0, stream);
    hipLaunchKernelGGL(dft_kernel, dim3(B / TM), dim3(BLOCK), 0, stream, x, out, B);
}